// Round 4
// baseline (183.107 us; speedup 1.0000x reference)
//
#include <hip/hip_runtime.h>

// TripletColbertLoss on MFMA: q (B,Q,D), p/n (B,K,D) fp32 -> scalar.
// loss = relu(0.2 + neg - pos), score = sum_{b,q} max_k q.d
// B=256 Q=256 K=512 D=128.
//
// R4: q-split grid (batch, pass, q-half) = 1024 blocks = exactly 4 blocks/CU
// (LDS 4x34.8=139 KB, VGPR capped 128 via __launch_bounds__(256,4)) ->
// 4 waves/SIMD latency hiding. Each wave owns 32 q-rows (mi=2), A-frags in
// registers (64 VGPR hi+lo). Docs stream through double-buffered hi/lo bf16
// LDS tiles. 3-term bf16 truncation split: Ahi*Bhi + Alo*Bhi + Ahi*Blo.
// Per-block signed partial -> one fp64 atomicAdd (exact accumulation).

#define MARGIN   0.2f
#define Bn       256
#define Qn       256
#define Kn       512
#define Dn       128
#define TN       32            // docs per tile
#define NT       (Kn / TN)     // 16 tiles
#define BSTR     136           // doc stride (bf16 units): 272 B, 16B-aligned, bank offset 4 (2-way, free)
#define NTHREADS 256
#define MI       2             // 16-row MFMA tiles per wave (32 q rows)

typedef __attribute__((ext_vector_type(8))) short short8;
typedef __attribute__((ext_vector_type(4))) short short4v;
typedef __attribute__((ext_vector_type(4))) float f32x4;

// Truncation split: x = hi + lo (both bf16). hi = truncate(x); lo captures the
// dropped 16 bits (trunc err ~2^-17 rel). Shift/mask only -> cheap VALU.
__device__ __forceinline__ void split_trunc(float x, unsigned short& hi, unsigned short& lo) {
    unsigned int u = __float_as_uint(x);
    hi = (unsigned short)(u >> 16);
    float l = x - __uint_as_float(u & 0xFFFF0000u);
    lo = (unsigned short)(__float_as_uint(l) >> 16);
}

__global__ __launch_bounds__(NTHREADS, 4)
void colbert_q4_kernel(const float* __restrict__ qg,
                       const float* __restrict__ pg,
                       const float* __restrict__ ng,
                       double* __restrict__ sum_ws) {
    __shared__ short Bs[2][2][TN * BSTR];   // [buf][hi/lo][doc*BSTR + dim]  34816 B
    __shared__ float part[4];

    const int tid  = threadIdx.x;
    const int w    = tid >> 6;
    const int lane = tid & 63;
    const int l16  = lane & 15;
    const int quad = lane >> 4;
    const int b    = blockIdx.x;
    const int pass = blockIdx.y;            // 0 -> p (+), 1 -> n (-)
    const int qh   = blockIdx.z;            // q-half: rows qh*128 .. +127

    const float* docb = (pass ? ng : pg) + (size_t)b * Kn * Dn;

    // Prefetch tile 0 before the A-conversion VALU burst.
    float4 pre[4];
    {
        const float4* s4 = (const float4*)docb;
#pragma unroll
        for (int k = 0; k < 4; ++k) pre[k] = s4[tid + 256 * k];
    }

    // ---- A fragments: 32 q-rows per wave, hi/lo bf16 in registers (64 VGPR).
    // 16x16x32 A layout: lane holds A[m = l16][k = quad*8 + j], j=0..7.
    short8 Ahi[MI][4], Alo[MI][4];          // [mi][ks]
    {
        const float* qb = qg + ((size_t)b * Qn + qh * 128) * Dn;
#pragma unroll
        for (int mi = 0; mi < MI; ++mi)
#pragma unroll
            for (int ks = 0; ks < 4; ++ks) {
                const float* src = qb + (size_t)(w * 32 + mi * 16 + l16) * Dn
                                      + ks * 32 + quad * 8;
                float4 v0 = *(const float4*)src;
                float4 v1 = *(const float4*)(src + 4);
                float x[8] = {v0.x, v0.y, v0.z, v0.w, v1.x, v1.y, v1.z, v1.w};
#pragma unroll
                for (int j = 0; j < 8; ++j) {
                    unsigned short h, l;
                    split_trunc(x[j], h, l);
                    Ahi[mi][ks][j] = (short)h;
                    Alo[mi][ks][j] = (short)l;
                }
            }
    }

    float maxv[MI][4];                      // [mi][reg] running row-max
#pragma unroll
    for (int mi = 0; mi < MI; ++mi)
#pragma unroll
        for (int r = 0; r < 4; ++r) maxv[mi][r] = -3e38f;

    int buf = 0;
    for (int t = 0; t < NT; ++t) {
        // convert tile t -> LDS[buf] (hi & lo planes)
#pragma unroll
        for (int k = 0; k < 4; ++k) {
            int i   = tid + 256 * k;
            int doc = i >> 5;              // 32 float4 per doc
            int d4  = i & 31;
            float4 v = pre[k];
            float x[4] = {v.x, v.y, v.z, v.w};
            short4v hi, lo;
#pragma unroll
            for (int j = 0; j < 4; ++j) {
                unsigned short h, l;
                split_trunc(x[j], h, l);
                hi[j] = (short)h;
                lo[j] = (short)l;
            }
            *(short4v*)&Bs[buf][0][doc * BSTR + d4 * 4] = hi;
            *(short4v*)&Bs[buf][1][doc * BSTR + d4 * 4] = lo;
        }
        __syncthreads();

        // prefetch tile t+1 while MFMAs run
        if (t + 1 < NT) {
            const float4* s4 = (const float4*)(docb + (size_t)(t + 1) * TN * Dn);
#pragma unroll
            for (int k = 0; k < 4; ++k) pre[k] = s4[tid + 256 * k];
        }

        f32x4 acc[MI][2];
#pragma unroll
        for (int mi = 0; mi < MI; ++mi)
#pragma unroll
            for (int ni = 0; ni < 2; ++ni) acc[mi][ni] = (f32x4){0.f, 0.f, 0.f, 0.f};

#pragma unroll
        for (int ni = 0; ni < 2; ++ni) {
#pragma unroll
            for (int ks = 0; ks < 4; ++ks) {
                int off = (ni * 16 + l16) * BSTR + ks * 32 + quad * 8;
                short8 bhi = *(const short8*)&Bs[buf][0][off];
                short8 blo = *(const short8*)&Bs[buf][1][off];
#pragma unroll
                for (int mi = 0; mi < MI; ++mi)
                    acc[mi][ni] = __builtin_amdgcn_mfma_f32_16x16x32_bf16(
                        Ahi[mi][ks], bhi, acc[mi][ni], 0, 0, 0);
#pragma unroll
                for (int mi = 0; mi < MI; ++mi)
                    acc[mi][ni] = __builtin_amdgcn_mfma_f32_16x16x32_bf16(
                        Alo[mi][ks], bhi, acc[mi][ni], 0, 0, 0);
#pragma unroll
                for (int mi = 0; mi < MI; ++mi)
                    acc[mi][ni] = __builtin_amdgcn_mfma_f32_16x16x32_bf16(
                        Ahi[mi][ks], blo, acc[mi][ni], 0, 0, 0);
            }
        }

        // C/D layout: col(doc)=l16, row=quad*4+reg
#pragma unroll
        for (int mi = 0; mi < MI; ++mi)
#pragma unroll
            for (int r = 0; r < 4; ++r)
                maxv[mi][r] = fmaxf(maxv[mi][r], fmaxf(acc[mi][0][r], acc[mi][1][r]));
        buf ^= 1;
    }

    // max over the 16 doc-column lanes
#pragma unroll
    for (int off = 1; off < 16; off <<= 1)
#pragma unroll
        for (int mi = 0; mi < MI; ++mi)
#pragma unroll
            for (int r = 0; r < 4; ++r)
                maxv[mi][r] = fmaxf(maxv[mi][r], __shfl_xor(maxv[mi][r], off));

    float s = 0.f;
#pragma unroll
    for (int mi = 0; mi < MI; ++mi)
#pragma unroll
        for (int r = 0; r < 4; ++r) s += maxv[mi][r];
    if (l16 != 0) s = 0.f;                  // one copy per quad
    s += __shfl_xor(s, 16);                 // combine the 4 quads
    s += __shfl_xor(s, 32);
    if (lane == 0) part[w] = s;
    __syncthreads();
    if (tid == 0) {
        double t = (double)part[0] + part[1] + part[2] + part[3];
        atomicAdd(sum_ws, pass ? -t : t);   // S = pos - neg, exact in fp64
    }
}

__global__ void finalize_kernel(const double* __restrict__ sum_ws,
                                float* __restrict__ out) {
    out[0] = fmaxf(0.0f, MARGIN - (float)sum_ws[0]);
}

extern "C" void kernel_launch(void* const* d_in, const int* in_sizes, int n_in,
                              void* d_out, int out_size, void* d_ws, size_t ws_size,
                              hipStream_t stream) {
    const float* q = (const float*)d_in[0];
    const float* p = (const float*)d_in[1];
    const float* n = (const float*)d_in[2];
    float* out = (float*)d_out;
    double* ws = (double*)d_ws;

    hipMemsetAsync(ws, 0, sizeof(double), stream);  // ws re-poisoned each call

    colbert_q4_kernel<<<dim3(Bn, 2, 2), NTHREADS, 0, stream>>>(q, p, n, ws);
    finalize_kernel<<<1, 1, 0, stream>>>(ws, out);
}